// Round 1
// baseline (207.137 us; speedup 1.0000x reference)
//
#include <hip/hip_runtime.h>
#include <hip/hip_bf16.h>
#include <stdint.h>

// Problem constants
#define B_  8
#define S_  1024
#define H_  1024
#define NH_ 16
#define HD_ 64
#define M_  (B_*S_)   // 8192 rows of hidden

using bf16x8 = __attribute__((ext_vector_type(8))) __bf16;
using f32x4  = __attribute__((ext_vector_type(4))) float;

// async global->LDS, 16B per lane; lds ptr must be wave-uniform (HW adds lane*16)
__device__ __forceinline__ void gload_lds16(const void* g, void* l) {
  __builtin_amdgcn_global_load_lds(
      (const __attribute__((address_space(1))) unsigned int*)g,
      (__attribute__((address_space(3))) unsigned int*)l, 16, 0, 0);
}

// ---------------------------------------------------------------------------
// fp32 -> bf16 cast, vectorized 8 elems/thread
// ---------------------------------------------------------------------------
__global__ void __launch_bounds__(256) cast_bf16_kernel(const float* __restrict__ in,
                                                        __bf16* __restrict__ out, int n8) {
  int i = blockIdx.x * blockDim.x + threadIdx.x;
  int stride = gridDim.x * blockDim.x;
  for (; i < n8; i += stride) {
    float4 f0 = ((const float4*)in)[2 * i];
    float4 f1 = ((const float4*)in)[2 * i + 1];
    bf16x8 o;
    o[0] = (__bf16)f0.x; o[1] = (__bf16)f0.y; o[2] = (__bf16)f0.z; o[3] = (__bf16)f0.w;
    o[4] = (__bf16)f1.x; o[5] = (__bf16)f1.y; o[6] = (__bf16)f1.z; o[7] = (__bf16)f1.w;
    ((bf16x8*)out)[i] = o;
  }
}

// ---------------------------------------------------------------------------
// QKV projection GEMM: C = X @ W^T + b    (X:[8192,1024] bf16, W:[1024,1024] bf16 [N,K])
// 128x128 tile, BK=64, 4 waves (2x2), each wave 64x64 via 4x4 of 16x16x32 MFMA.
// LDS tiles [128][64] bf16 with XOR swizzle: tile byte p stored at p ^ ((row&7)<<4).
// Outputs: z=0 -> Q [B,NH,S,HD] *0.125 ; z=1 -> K [B,NH,S,HD] ; z=2 -> V^T [B,NH,HD,S]
// ---------------------------------------------------------------------------
__global__ void __launch_bounds__(256) qkv_gemm_kernel(
    const __bf16* __restrict__ X,
    const __bf16* __restrict__ Wq, const __bf16* __restrict__ Wk, const __bf16* __restrict__ Wv,
    const float* __restrict__ bq, const float* __restrict__ bk, const float* __restrict__ bv,
    __bf16* __restrict__ Qo, __bf16* __restrict__ Ko, __bf16* __restrict__ Vto) {
  __shared__ __align__(16) char Asm[128 * 128];  // [128][64] bf16 = 16 KB
  __shared__ __align__(16) char Bsm[128 * 128];

  const int tid = threadIdx.x;
  const int lane = tid & 63, w = tid >> 6;
  const int l15 = lane & 15, g = lane >> 4;
  const int wr = w >> 1, wc = w & 1;
  const int m0 = blockIdx.x * 128;
  const int n0 = blockIdx.y * 128;
  const int z = blockIdx.z;
  const __bf16* W = (z == 0) ? Wq : ((z == 1) ? Wk : Wv);
  const float* bias = (z == 0) ? bq : ((z == 1) ? bk : bv);

  f32x4 acc[4][4] = {};

  for (int kt = 0; kt < H_; kt += 64) {
    __syncthreads();
    // stage A[128][64] and B[128][64], pre-swizzled global source
#pragma unroll
    for (int is = 0; is < 4; ++is) {
      int q = is * 4096 + tid * 16;            // linear LDS byte this lane fills
      int row = q >> 7;                        // 128B rows
      int inrow = (q & 127) ^ ((row & 7) << 4);
      const char* ga = (const char*)X + (size_t)(m0 + row) * (H_ * 2) + kt * 2 + inrow;
      const char* gb = (const char*)W + (size_t)(n0 + row) * (H_ * 2) + kt * 2 + inrow;
      gload_lds16(ga, Asm + is * 4096 + w * 1024);
      gload_lds16(gb, Bsm + is * 4096 + w * 1024);
    }
    __syncthreads();
#pragma unroll
    for (int ks = 0; ks < 2; ++ks) {
      bf16x8 a[4], b[4];
#pragma unroll
      for (int i = 0; i < 4; ++i) {
        int row = wr * 64 + i * 16 + l15;
        int chunk = (g + ks * 4) ^ (row & 7);
        a[i] = *reinterpret_cast<const bf16x8*>(Asm + row * 128 + chunk * 16);
      }
#pragma unroll
      for (int j = 0; j < 4; ++j) {
        int row = wc * 64 + j * 16 + l15;
        int chunk = (g + ks * 4) ^ (row & 7);
        b[j] = *reinterpret_cast<const bf16x8*>(Bsm + row * 128 + chunk * 16);
      }
#pragma unroll
      for (int i = 0; i < 4; ++i)
#pragma unroll
        for (int j = 0; j < 4; ++j)
          acc[i][j] = __builtin_amdgcn_mfma_f32_16x16x32_bf16(a[i], b[j], acc[i][j], 0, 0, 0);
    }
  }

  // epilogue: C/D layout row=4g+r, col=l15 per 16x16 frag
#pragma unroll
  for (int i = 0; i < 4; ++i) {
#pragma unroll
    for (int j = 0; j < 4; ++j) {
      int n = n0 + wc * 64 + j * 16 + l15;
      float bs = bias[n];
      int nh = n >> 6, d = n & 63;
#pragma unroll
      for (int r = 0; r < 4; ++r) {
        int m = m0 + wr * 64 + i * 16 + 4 * g + r;
        int bb = m >> 10, s = m & 1023;
        float v = acc[i][j][r] + bs;
        if (z == 0) {
          Qo[(((size_t)bb * NH_ + nh) * S_ + s) * HD_ + d] = (__bf16)(v * 0.125f);
        } else if (z == 1) {
          Ko[(((size_t)bb * NH_ + nh) * S_ + s) * HD_ + d] = (__bf16)v;
        } else {
          Vto[(((size_t)bb * NH_ + nh) * HD_ + d) * S_ + s] = (__bf16)v;
        }
      }
    }
  }
}

// ---------------------------------------------------------------------------
// Flash attention: per block = 64 q-rows of one head; 4 waves x 16 q-rows.
// KV loop 64 keys/iter. K tile [64 keys][64 d], Vt tile [64 d][64 keys], both
// swizzled in LDS. Online softmax; P through per-wave swizzled LDS tile.
// Q is pre-scaled by 0.125 in the projection.
// ---------------------------------------------------------------------------
__global__ void __launch_bounds__(256) attn_kernel(
    const __bf16* __restrict__ Q,   // [128][1024][64]
    const __bf16* __restrict__ K,   // [128][1024][64]
    const __bf16* __restrict__ Vt,  // [128][64][1024]
    float* __restrict__ Out) {      // [8][1024][1024]
  __shared__ __align__(16) char Ksm[8192];
  __shared__ __align__(16) char Vsm[8192];
  __shared__ __align__(16) char Psm[8192];  // 4 waves x [16][64] bf16

  const int tid = threadIdx.x, lane = tid & 63, w = tid >> 6;
  const int l15 = lane & 15, g = lane >> 4;
  const int head = blockIdx.y;
  const int bb = head >> 4, nh = head & 15;
  const int q0 = blockIdx.x * 64;

  const char* Qh = (const char*)(Q + (size_t)head * S_ * HD_);
  const char* Kh = (const char*)(K + (size_t)head * S_ * HD_);
  const char* Vh = (const char*)(Vt + (size_t)head * S_ * HD_);  // [64][1024]

  // hoist Q fragments: A-frag row = l15, k = 8g+j (+32 per ks)
  const int qrow = q0 + w * 16 + l15;
  bf16x8 qf[2];
  qf[0] = *reinterpret_cast<const bf16x8*>(Qh + (size_t)qrow * 128 + g * 16);
  qf[1] = *reinterpret_cast<const bf16x8*>(Qh + (size_t)qrow * 128 + 64 + g * 16);

  float mrun[4], lrun[4];
  f32x4 acc[4] = {};
#pragma unroll
  for (int r = 0; r < 4; ++r) { mrun[r] = -1e30f; lrun[r] = 0.0f; }

  for (int kv = 0; kv < S_; kv += 64) {
    __syncthreads();
#pragma unroll
    for (int is = 0; is < 2; ++is) {
      int q = is * 4096 + tid * 16;
      int row = q >> 7;
      int inrow = (q & 127) ^ ((row & 7) << 4);
      gload_lds16(Kh + (size_t)(kv + row) * 128 + inrow, Ksm + is * 4096 + w * 1024);
      gload_lds16(Vh + (size_t)row * 2048 + kv * 2 + inrow, Vsm + is * 4096 + w * 1024);
    }
    __syncthreads();

    // QK^T -> sc[kt] (rows 4g+r, cols kt*16+l15)
    f32x4 sc[4];
#pragma unroll
    for (int ktile = 0; ktile < 4; ++ktile) {
      f32x4 c = {};
#pragma unroll
      for (int ks = 0; ks < 2; ++ks) {
        int row = ktile * 16 + l15;
        int chunk = (g + ks * 4) ^ (row & 7);
        bf16x8 bfr = *reinterpret_cast<const bf16x8*>(Ksm + row * 128 + chunk * 16);
        c = __builtin_amdgcn_mfma_f32_16x16x32_bf16(qf[ks], bfr, c, 0, 0, 0);
      }
      sc[ktile] = c;
    }

    // online softmax per q-row (replicated across the 16-lane group)
#pragma unroll
    for (int r = 0; r < 4; ++r) {
      float t = fmaxf(fmaxf(sc[0][r], sc[1][r]), fmaxf(sc[2][r], sc[3][r]));
      t = fmaxf(t, __shfl_xor(t, 1));
      t = fmaxf(t, __shfl_xor(t, 2));
      t = fmaxf(t, __shfl_xor(t, 4));
      t = fmaxf(t, __shfl_xor(t, 8));
      float mnew = fmaxf(mrun[r], t);
      float corr = __expf(mrun[r] - mnew);
      float ps = 0.0f;
#pragma unroll
      for (int ktile = 0; ktile < 4; ++ktile) {
        float p = __expf(sc[ktile][r] - mnew);
        sc[ktile][r] = p;
        ps += p;
      }
      ps += __shfl_xor(ps, 1);
      ps += __shfl_xor(ps, 2);
      ps += __shfl_xor(ps, 4);
      ps += __shfl_xor(ps, 8);
      lrun[r] = lrun[r] * corr + ps;
      mrun[r] = mnew;
#pragma unroll
      for (int j = 0; j < 4; ++j) acc[j][r] *= corr;
    }

    // P (bf16) -> per-wave swizzled LDS tile [16][64]
    {
      char* P = Psm + w * 2048;
#pragma unroll
      for (int ktile = 0; ktile < 4; ++ktile)
#pragma unroll
        for (int r = 0; r < 4; ++r) {
          int row = 4 * g + r;
          int col = ktile * 16 + l15;
          int off = row * 128 + (((col >> 3) ^ (row & 7)) << 4) + (col & 7) * 2;
          *(__bf16*)(P + off) = (__bf16)sc[ktile][r];
        }
    }
    __syncthreads();

    // PV: acc[j] += P[16x64] @ V[64 x 16d(j)]
    const char* P = Psm + w * 2048;
#pragma unroll
    for (int ks = 0; ks < 2; ++ks) {
      int prow = l15;
      int pchunk = (g + 4 * ks) ^ (prow & 7);
      bf16x8 pa = *reinterpret_cast<const bf16x8*>(P + prow * 128 + pchunk * 16);
#pragma unroll
      for (int j = 0; j < 4; ++j) {
        int vrow = j * 16 + l15;
        int vchunk = (g + 4 * ks) ^ (vrow & 7);
        bf16x8 vb = *reinterpret_cast<const bf16x8*>(Vsm + vrow * 128 + vchunk * 16);
        acc[j] = __builtin_amdgcn_mfma_f32_16x16x32_bf16(pa, vb, acc[j], 0, 0, 0);
      }
    }
  }

  // epilogue: out[b][s][nh*64+d] = acc/l
  float* Ob = Out + (size_t)bb * S_ * H_ + (size_t)nh * HD_;
#pragma unroll
  for (int r = 0; r < 4; ++r) {
    float inv = 1.0f / lrun[r];
    int s = q0 + w * 16 + 4 * g + r;
#pragma unroll
    for (int j = 0; j < 4; ++j) {
      int d = j * 16 + l15;
      Ob[(size_t)s * H_ + d] = acc[j][r] * inv;
    }
  }
}

// ---------------------------------------------------------------------------
extern "C" void kernel_launch(void* const* d_in, const int* in_sizes, int n_in,
                              void* d_out, int out_size, void* d_ws, size_t ws_size,
                              hipStream_t stream) {
  const float* hs = (const float*)d_in[0];
  const float* Wq = (const float*)d_in[1];
  const float* bq = (const float*)d_in[2];
  const float* Wk = (const float*)d_in[3];
  const float* bk = (const float*)d_in[4];
  const float* Wv = (const float*)d_in[5];
  const float* bv = (const float*)d_in[6];
  float* out = (float*)d_out;
  char* ws = (char*)d_ws;

  size_t off = 0;
  __bf16* Xb  = (__bf16*)(ws + off); off += (size_t)M_ * H_ * 2;   // 16.8 MB
  __bf16* Wqb = (__bf16*)(ws + off); off += (size_t)H_ * H_ * 2;
  __bf16* Wkb = (__bf16*)(ws + off); off += (size_t)H_ * H_ * 2;
  __bf16* Wvb = (__bf16*)(ws + off); off += (size_t)H_ * H_ * 2;
  __bf16* Qb  = (__bf16*)(ws + off); off += (size_t)M_ * H_ * 2;
  __bf16* Kb  = (__bf16*)(ws + off); off += (size_t)M_ * H_ * 2;
  __bf16* Vtb = (__bf16*)(ws + off); off += (size_t)M_ * H_ * 2;
  // total ~73.4 MB of d_ws

  cast_bf16_kernel<<<4096, 256, 0, stream>>>(hs, Xb, M_ * H_ / 8);
  cast_bf16_kernel<<<512, 256, 0, stream>>>(Wq, Wqb, H_ * H_ / 8);
  cast_bf16_kernel<<<512, 256, 0, stream>>>(Wk, Wkb, H_ * H_ / 8);
  cast_bf16_kernel<<<512, 256, 0, stream>>>(Wv, Wvb, H_ * H_ / 8);

  qkv_gemm_kernel<<<dim3(M_ / 128, H_ / 128, 3), 256, 0, stream>>>(
      Xb, Wqb, Wkb, Wvb, bq, bk, bv, Qb, Kb, Vtb);

  attn_kernel<<<dim3(S_ / 64, B_ * NH_), 256, 0, stream>>>(Qb, Kb, Vtb, out);
}

// Round 2
// 160.061 us; speedup vs baseline: 1.2941x; 1.2941x over previous
//
#include <hip/hip_runtime.h>
#include <hip/hip_bf16.h>
#include <stdint.h>

// Problem constants
#define B_  8
#define S_  1024
#define H_  1024
#define NH_ 16
#define HD_ 64
#define M_  (B_*S_)   // 8192 rows of hidden

using bf16x8 = __attribute__((ext_vector_type(8))) __bf16;
using f32x4  = __attribute__((ext_vector_type(4))) float;
using f32x16 = __attribute__((ext_vector_type(16))) float;
typedef int iv2 __attribute__((ext_vector_type(2)));

#define LOG2E 1.4426950408889634f

#if __has_builtin(__builtin_amdgcn_exp2f)
#define EXP2(x) __builtin_amdgcn_exp2f(x)
#else
#define EXP2(x) exp2f(x)
#endif

// async global->LDS, 16B per lane; lds ptr must be wave-uniform (HW adds lane*16)
__device__ __forceinline__ void gload_lds16(const void* g, void* l) {
  __builtin_amdgcn_global_load_lds(
      (const __attribute__((address_space(1))) unsigned int*)g,
      (__attribute__((address_space(3))) unsigned int*)l, 16, 0, 0);
}

// pack two f32 -> one u32 of 2 bf16 (lo in bits 0-15)
__device__ __forceinline__ unsigned pack_bf16(float lo, float hi) {
  unsigned r;
  asm("v_cvt_pk_bf16_f32 %0, %1, %2" : "=v"(r) : "v"(lo), "v"(hi));
  return r;
}

// swap a.hi32lanes <-> b.lo32lanes
__device__ __forceinline__ void swapl32(unsigned& a, unsigned& b) {
#if __has_builtin(__builtin_amdgcn_permlane32_swap)
  iv2 r = __builtin_amdgcn_permlane32_swap((int)a, (int)b, false, false);
  a = (unsigned)r[0];
  b = (unsigned)r[1];
#else
  unsigned axc = (unsigned)__shfl_xor((int)a, 32);
  unsigned bxc = (unsigned)__shfl_xor((int)b, 32);
  int lane = threadIdx.x & 63;
  unsigned an = (lane < 32) ? a : bxc;
  unsigned bn = (lane < 32) ? axc : b;
  a = an; b = bn;
#endif
}

// ---------------------------------------------------------------------------
// fp32 -> bf16 cast, vectorized 8 elems/thread
// ---------------------------------------------------------------------------
__global__ void __launch_bounds__(256) cast_bf16_kernel(const float* __restrict__ in,
                                                        __bf16* __restrict__ out, int n8) {
  int i = blockIdx.x * blockDim.x + threadIdx.x;
  int stride = gridDim.x * blockDim.x;
  for (; i < n8; i += stride) {
    float4 f0 = ((const float4*)in)[2 * i];
    float4 f1 = ((const float4*)in)[2 * i + 1];
    bf16x8 o;
    o[0] = (__bf16)f0.x; o[1] = (__bf16)f0.y; o[2] = (__bf16)f0.z; o[3] = (__bf16)f0.w;
    o[4] = (__bf16)f1.x; o[5] = (__bf16)f1.y; o[6] = (__bf16)f1.z; o[7] = (__bf16)f1.w;
    ((bf16x8*)out)[i] = o;
  }
}

// ---------------------------------------------------------------------------
// QKV projection GEMM: C = X @ W^T + b   (unchanged from round 1 — validated)
// Outputs: z=0 -> Q [B,NH,S,HD] * (0.125*log2e) ; z=1 -> K ; z=2 -> V^T [B,NH,HD,S]
// ---------------------------------------------------------------------------
__global__ void __launch_bounds__(256) qkv_gemm_kernel(
    const __bf16* __restrict__ X,
    const __bf16* __restrict__ Wq, const __bf16* __restrict__ Wk, const __bf16* __restrict__ Wv,
    const float* __restrict__ bq, const float* __restrict__ bk, const float* __restrict__ bv,
    __bf16* __restrict__ Qo, __bf16* __restrict__ Ko, __bf16* __restrict__ Vto) {
  __shared__ __align__(16) char Asm[128 * 128];
  __shared__ __align__(16) char Bsm[128 * 128];

  const int tid = threadIdx.x;
  const int lane = tid & 63, w = tid >> 6;
  const int l15 = lane & 15, g = lane >> 4;
  const int wr = w >> 1, wc = w & 1;
  const int m0 = blockIdx.x * 128;
  const int n0 = blockIdx.y * 128;
  const int z = blockIdx.z;
  const __bf16* W = (z == 0) ? Wq : ((z == 1) ? Wk : Wv);
  const float* bias = (z == 0) ? bq : ((z == 1) ? bk : bv);

  f32x4 acc[4][4] = {};

  for (int kt = 0; kt < H_; kt += 64) {
    __syncthreads();
#pragma unroll
    for (int is = 0; is < 4; ++is) {
      int q = is * 4096 + tid * 16;
      int row = q >> 7;
      int inrow = (q & 127) ^ ((row & 7) << 4);
      const char* ga = (const char*)X + (size_t)(m0 + row) * (H_ * 2) + kt * 2 + inrow;
      const char* gb = (const char*)W + (size_t)(n0 + row) * (H_ * 2) + kt * 2 + inrow;
      gload_lds16(ga, Asm + is * 4096 + w * 1024);
      gload_lds16(gb, Bsm + is * 4096 + w * 1024);
    }
    __syncthreads();
#pragma unroll
    for (int ks = 0; ks < 2; ++ks) {
      bf16x8 a[4], b[4];
#pragma unroll
      for (int i = 0; i < 4; ++i) {
        int row = wr * 64 + i * 16 + l15;
        int chunk = (g + ks * 4) ^ (row & 7);
        a[i] = *reinterpret_cast<const bf16x8*>(Asm + row * 128 + chunk * 16);
      }
#pragma unroll
      for (int j = 0; j < 4; ++j) {
        int row = wc * 64 + j * 16 + l15;
        int chunk = (g + ks * 4) ^ (row & 7);
        b[j] = *reinterpret_cast<const bf16x8*>(Bsm + row * 128 + chunk * 16);
      }
#pragma unroll
      for (int i = 0; i < 4; ++i)
#pragma unroll
        for (int j = 0; j < 4; ++j)
          acc[i][j] = __builtin_amdgcn_mfma_f32_16x16x32_bf16(a[i], b[j], acc[i][j], 0, 0, 0);
    }
  }

#pragma unroll
  for (int i = 0; i < 4; ++i) {
#pragma unroll
    for (int j = 0; j < 4; ++j) {
      int n = n0 + wc * 64 + j * 16 + l15;
      float bs = bias[n];
      int nh = n >> 6, d = n & 63;
#pragma unroll
      for (int r = 0; r < 4; ++r) {
        int m = m0 + wr * 64 + i * 16 + 4 * g + r;
        int bb = m >> 10, s = m & 1023;
        float v = acc[i][j][r] + bs;
        if (z == 0) {
          // Q scaled by 1/sqrt(64) * log2(e)  (exp2-domain softmax)
          Qo[(((size_t)bb * NH_ + nh) * S_ + s) * HD_ + d] = (__bf16)(v * (0.125f * LOG2E));
        } else if (z == 1) {
          Ko[(((size_t)bb * NH_ + nh) * S_ + s) * HD_ + d] = (__bf16)v;
        } else {
          Vto[(((size_t)bb * NH_ + nh) * HD_ + d) * S_ + s] = (__bf16)v;
        }
      }
    }
  }
}

// ---------------------------------------------------------------------------
// Flash attention, 8-wave 32x32 structure (guide §B):
//  - block = 256 q-rows of one head, 8 waves x 32 q-rows, KVBLK=64
//  - swapped QK^T: S_kq = mfma(A=K, B=Q) -> lane holds P[k=...][q=lane&31]
//  - in-register softmax (31 fmax + 1 shfl_xor(32)), exp2 domain
//  - P -> PV A-frag via v_cvt_pk_bf16_f32 + permlane32_swap (no LDS for P)
//  - stats redistributed lane-space -> reg-space via 32-float LDS broadcast
// ---------------------------------------------------------------------------
#define CROW(r, hi) (((r) & 3) + 8 * ((r) >> 2) + 4 * (hi))

__global__ void __launch_bounds__(512) attn_kernel(
    const __bf16* __restrict__ Q,   // [128][1024][64]
    const __bf16* __restrict__ K,   // [128][1024][64]
    const __bf16* __restrict__ Vt,  // [128][64][1024]
    float* __restrict__ Out) {      // [8][1024][1024]
  __shared__ __align__(16) char Ksm[8192];   // [64 keys][64 d] bf16, chunk-swizzled
  __shared__ __align__(16) char Vsm[8192];   // [64 d][64 keys] bf16, chunk-swizzled
  __shared__ __align__(16) float stat_lds[512];  // 8 waves x 64 (only [0,32) of each used)

  const int tid = threadIdx.x, lane = tid & 63, w = tid >> 6;
  const int l31 = lane & 31, hi = lane >> 5;
  const int head = blockIdx.y;
  const int bb = head >> 4, nh = head & 15;
  const int qw = blockIdx.x * 256 + w * 32;  // this wave's q base

  const char* Qh = (const char*)(Q + (size_t)head * S_ * HD_);
  const char* Kh = (const char*)(K + (size_t)head * S_ * HD_);
  const char* Vh = (const char*)(Vt + (size_t)head * S_ * HD_);  // [64][1024]

  // Q as B-operand fragments: B[col=q=lane&31][t=d=16*slot+8*hi+j]
  bf16x8 qf[4];
#pragma unroll
  for (int slot = 0; slot < 4; ++slot)
    qf[slot] = *reinterpret_cast<const bf16x8*>(
        Qh + (size_t)(qw + l31) * 128 + slot * 32 + hi * 16);

  float m_run = -1e30f, l_run = 0.0f;
  f32x16 accO[2] = {};  // O[q=CROW(r,hi)][d = dt*32 + l31]

  for (int kv = 0; kv < S_; kv += 64) {
    __syncthreads();
    {
      int q = tid * 16;
      int row = q >> 7;
      int inrow = (q & 127) ^ ((row & 7) << 4);
      gload_lds16(Kh + (size_t)(kv + row) * 128 + inrow, Ksm + w * 1024);
      gload_lds16(Vh + (size_t)row * 2048 + kv * 2 + inrow, Vsm + w * 1024);
    }
    __syncthreads();

    // ---- QK^T (swapped): s0 = keys 0..31, s1 = keys 32..63; col = q = l31
    f32x16 s0 = {}, s1 = {};
#pragma unroll
    for (int slot = 0; slot < 4; ++slot) {
      int c0 = slot * 2 + hi;
      int r0 = l31;
      bf16x8 k0 = *reinterpret_cast<const bf16x8*>(Ksm + r0 * 128 + ((c0 ^ (r0 & 7)) << 4));
      int r1 = 32 + l31;
      bf16x8 k1 = *reinterpret_cast<const bf16x8*>(Ksm + r1 * 128 + ((c0 ^ (r1 & 7)) << 4));
      s0 = __builtin_amdgcn_mfma_f32_32x32x16_bf16(k0, qf[slot], s0, 0, 0, 0);
      s1 = __builtin_amdgcn_mfma_f32_32x32x16_bf16(k1, qf[slot], s1, 0, 0, 0);
    }

    // ---- online softmax (exp2 domain; scores pre-scaled by 0.125*log2e via Q)
    float mx = -1e30f;
#pragma unroll
    for (int r = 0; r < 16; ++r) mx = fmaxf(mx, fmaxf(s0[r], s1[r]));
    mx = fmaxf(mx, __shfl_xor(mx, 32));
    float mnew = fmaxf(m_run, mx);
    float corr = EXP2(m_run - mnew);
    float sum = 0.0f;
#pragma unroll
    for (int r = 0; r < 16; ++r) {
      float p0 = EXP2(s0[r] - mnew); s0[r] = p0; sum += p0;
      float p1 = EXP2(s1[r] - mnew); s1[r] = p1; sum += p1;
    }
    sum += __shfl_xor(sum, 32);
    l_run = l_run * corr + sum;
    m_run = mnew;

    // redistribute corr (lane-space q=l31) -> reg-space rows
    stat_lds[w * 64 + lane] = corr;
    f32x4 c4[4];
#pragma unroll
    for (int rq = 0; rq < 4; ++rq)
      c4[rq] = *reinterpret_cast<const f32x4*>(&stat_lds[w * 64 + rq * 8 + hi * 4]);
#pragma unroll
    for (int r = 0; r < 16; ++r) {
      float cr = c4[r >> 2][r & 3];
      accO[0][r] *= cr;
      accO[1][r] *= cr;
    }

    // ---- P -> A-fragments (in-register, cvt_pk + permlane32_swap)
    bf16x8 pa[4];
#define BUILD_PA(T, rb)                                                     \
    {                                                                       \
      unsigned x1 = pack_bf16(T[rb + 0], T[rb + 1]);                        \
      unsigned x2 = pack_bf16(T[rb + 2], T[rb + 3]);                        \
      unsigned y1 = pack_bf16(T[rb + 4], T[rb + 5]);                        \
      unsigned y2 = pack_bf16(T[rb + 6], T[rb + 7]);                        \
      swapl32(x1, y1);                                                      \
      swapl32(x2, y2);                                                      \
      union { unsigned u[4]; bf16x8 v; } cvt;                               \
      cvt.u[0] = x1; cvt.u[1] = x2; cvt.u[2] = y1; cvt.u[3] = y2;           \
      pa_out = cvt.v;                                                       \
    }
    {
      bf16x8 pa_out;
      BUILD_PA(s0, 0) pa[0] = pa_out;
      BUILD_PA(s0, 8) pa[1] = pa_out;
      BUILD_PA(s1, 0) pa[2] = pa_out;
      BUILD_PA(s1, 8) pa[3] = pa_out;
    }

    // ---- PV: accO[dt] += P[q][16ks..] @ V[16ks..][dt*32 + l31]
#pragma unroll
    for (int ks = 0; ks < 4; ++ks) {
#pragma unroll
      for (int dt = 0; dt < 2; ++dt) {
        int rd = dt * 32 + l31;
        int ck = ks * 2 + hi;
        bf16x8 vb = *reinterpret_cast<const bf16x8*>(Vsm + rd * 128 + ((ck ^ (rd & 7)) << 4));
        accO[dt] = __builtin_amdgcn_mfma_f32_32x32x16_bf16(pa[ks], vb, accO[dt], 0, 0, 0);
      }
    }
  }

  // ---- epilogue: redistribute 1/l to reg-space, scale, store
  stat_lds[w * 64 + lane] = 1.0f / l_run;
  f32x4 li4[4];
#pragma unroll
  for (int rq = 0; rq < 4; ++rq)
    li4[rq] = *reinterpret_cast<const f32x4*>(&stat_lds[w * 64 + rq * 8 + hi * 4]);

  float* Ob = Out + (size_t)bb * S_ * H_ + (size_t)nh * HD_;
#pragma unroll
  for (int r = 0; r < 16; ++r) {
    int qabs = qw + CROW(r, hi);
    float li = li4[r >> 2][r & 3];
#pragma unroll
    for (int dt = 0; dt < 2; ++dt) {
      int d = dt * 32 + l31;
      Ob[(size_t)qabs * H_ + d] = accO[dt][r] * li;
    }
  }
}

// ---------------------------------------------------------------------------
extern "C" void kernel_launch(void* const* d_in, const int* in_sizes, int n_in,
                              void* d_out, int out_size, void* d_ws, size_t ws_size,
                              hipStream_t stream) {
  const float* hs = (const float*)d_in[0];
  const float* Wq = (const float*)d_in[1];
  const float* bq = (const float*)d_in[2];
  const float* Wk = (const float*)d_in[3];
  const float* bk = (const float*)d_in[4];
  const float* Wv = (const float*)d_in[5];
  const float* bv = (const float*)d_in[6];
  float* out = (float*)d_out;
  char* ws = (char*)d_ws;

  size_t off = 0;
  __bf16* Xb  = (__bf16*)(ws + off); off += (size_t)M_ * H_ * 2;
  __bf16* Wqb = (__bf16*)(ws + off); off += (size_t)H_ * H_ * 2;
  __bf16* Wkb = (__bf16*)(ws + off); off += (size_t)H_ * H_ * 2;
  __bf16* Wvb = (__bf16*)(ws + off); off += (size_t)H_ * H_ * 2;
  __bf16* Qb  = (__bf16*)(ws + off); off += (size_t)M_ * H_ * 2;
  __bf16* Kb  = (__bf16*)(ws + off); off += (size_t)M_ * H_ * 2;
  __bf16* Vtb = (__bf16*)(ws + off); off += (size_t)M_ * H_ * 2;

  cast_bf16_kernel<<<4096, 256, 0, stream>>>(hs, Xb, M_ * H_ / 8);
  cast_bf16_kernel<<<512, 256, 0, stream>>>(Wq, Wqb, H_ * H_ / 8);
  cast_bf16_kernel<<<512, 256, 0, stream>>>(Wk, Wkb, H_ * H_ / 8);
  cast_bf16_kernel<<<512, 256, 0, stream>>>(Wv, Wvb, H_ * H_ / 8);

  qkv_gemm_kernel<<<dim3(M_ / 128, H_ / 128, 3), 256, 0, stream>>>(
      Xb, Wqb, Wkb, Wvb, bq, bk, bv, Qb, Kb, Vtb);

  attn_kernel<<<dim3(S_ / 256, B_ * NH_), 512, 0, stream>>>(Qb, Kb, Vtb, out);
}